// Round 5
// baseline (1756.399 us; speedup 1.0000x reference)
//
#include <hip/hip_runtime.h>
#include <hip/hip_bf16.h>

#define M_NODES 100
#define HDIM 512
#define MH (M_NODES*HDIM)       // 51200
#define MM2 (M_NODES*M_NODES)   // 10000

// child = relu(parent @ W_parent + b_parent)  -> [100,512] flattened [51200]
__global__ void child_kernel(const float* __restrict__ parent, const float* __restrict__ Wp,
                             const float* __restrict__ bp, float* __restrict__ child0) {
    __shared__ float p[HDIM];
    int tid = threadIdx.x;
    for (int i = tid; i < HDIM; i += 256) p[i] = parent[i];
    __syncthreads();
    int o = blockIdx.x * 256 + tid;            // < 51200
    float acc = bp[o];
    #pragma unroll 4
    for (int k = 0; k < HDIM; ++k) acc += p[k] * Wp[(size_t)k * MH + o];
    child0[o] = fmaxf(acc, 0.f);
}

// exists_logits[m] = child0[m,:] . W_exists + b_exists ; node_ok[m] = logit > 0
__global__ void exists_kernel(const float* __restrict__ child0, const float* __restrict__ Wex,
                              const float* __restrict__ bex, float* __restrict__ exists,
                              int* __restrict__ node_ok) {
    int m = blockIdx.x, tid = threadIdx.x;
    float s = 0.f;
    for (int k = tid; k < HDIM; k += 256) s += child0[m * HDIM + k] * Wex[k];
    __shared__ float red[256];
    red[tid] = s; __syncthreads();
    for (int st = 128; st > 0; st >>= 1) {
        if (tid < st) red[tid] += red[tid + st];
        __syncthreads();
    }
    if (tid == 0) {
        float v = red[0] + bex[0];
        exists[m] = v;
        node_ok[m] = (v > 0.f) ? 1 : 0;
    }
}

// Generic GEMM: C[m,n] = (relu?)( sum_k A[m,k]*B[k,n] + bias[n] )
// A: f32 [M,K] row-major, or (perm=1) A[m,k] = Abase[(k>>9)*MH + m*512 + (k&511)]
// B: f32 row-major [K,N]; C: f32 [M,N]
// grid: (ceil(N/256), ceil(M/TM)), block 256. K multiple of 256.
template<int TM>
__global__ void gemm_kernel(const float* __restrict__ A, const float* __restrict__ B,
                            const float* __restrict__ bias, float* __restrict__ C,
                            int M, int N, int K, int do_relu, int perm) {
    const int KC = 256;
    __shared__ float As[TM][KC];
    int n = blockIdx.x * 256 + threadIdx.x;
    int m0 = blockIdx.y * TM;
    float acc[TM];
    #pragma unroll
    for (int mm = 0; mm < TM; ++mm) acc[mm] = 0.f;
    for (int kc = 0; kc < K; kc += KC) {
        for (int idx = threadIdx.x; idx < TM * KC; idx += 256) {
            int mm = idx / KC, kk = idx % KC;
            int m = m0 + mm;
            float av = 0.f;
            if (m < M) {
                int k = kc + kk;
                av = perm ? A[(k >> 9) * MH + m * HDIM + (k & 511)]
                          : A[(size_t)m * K + k];
            }
            As[mm][kk] = av;
        }
        __syncthreads();
        if (n < N) {
            for (int kk = 0; kk < KC; ++kk) {
                float bv = B[(size_t)(kc + kk) * N + n];
                #pragma unroll
                for (int mm = 0; mm < TM; ++mm) acc[mm] += As[mm][kk] * bv;
            }
        }
        __syncthreads();
    }
    if (n < N) {
        float bs = bias ? bias[n] : 0.f;
        #pragma unroll
        for (int mm = 0; mm < TM; ++mm) {
            int m = m0 + mm;
            if (m < M) {
                float v = acc[mm] + bs;
                if (do_relu) v = fmaxf(v, 0.f);
                C[(size_t)m * N + n] = v;
            }
        }
    }
}

// elog[i,j,t] = relu(Xi[i]+Xj[j]) . W_ee[t] + b_ee[t] ; any_edge flag
__global__ void elog_kernel(const float* __restrict__ Xi, const float* __restrict__ Xj,
                            const float* __restrict__ Wee, const float* __restrict__ bee,
                            const int* __restrict__ node_ok,
                            float* __restrict__ elog, int* __restrict__ any_flag) {
    int ij = blockIdx.x;
    int i = ij / M_NODES, j = ij - i * M_NODES;
    int h = threadIdx.x;                         // 512 threads
    float v = fmaxf(Xi[i * HDIM + h] + Xj[j * HDIM + h], 0.f);
    __shared__ float red[4][HDIM];
    #pragma unroll
    for (int t = 0; t < 4; ++t) red[t][h] = v * Wee[t * HDIM + h];
    __syncthreads();
    for (int st = 256; st > 0; st >>= 1) {
        if (h < st) {
            #pragma unroll
            for (int t = 0; t < 4; ++t) red[t][h] += red[t][h + st];
        }
        __syncthreads();
    }
    if (h == 0) {
        bool ok = node_ok[i] && node_ok[j];
        bool any = false;
        #pragma unroll
        for (int t = 0; t < 4; ++t) {
            float lg = red[t][0] + bee[t];
            elog[ij * 4 + t] = lg;
            if (ok && lg > 0.f) any = true;
        }
        if (any) atomicOr(any_flag, 1);
    }
}

// Fully fused message step for iteration `it`:
//   new_child[i,h] = sum_{j,t} mask[i,j,t]*relu(A[i,h]+B[j,h]+C[i,j,h]+lg*W4[t,h])
//   C[i,j,h] = sum_k relu(Xi[i,k]+Xj[j,k]) * W3[k,h]     (never materialized)
// grid: dim3(2 /*h-seg*/, 100 /*i*/), block 256.
// Thread: tx = t&63 owns h-quad h0 = hseg*256+tx*4 ; ty = t>>6 covers j subset.
#define JT 20
#define KCF 128
__global__ void msgfused_kernel(const float* __restrict__ Xi, const float* __restrict__ Xj,
                                const float* __restrict__ Abuf, const float* __restrict__ Bbuf,
                                const float* __restrict__ W3, const float* __restrict__ W4,
                                const float* __restrict__ elog, const int* __restrict__ node_ok,
                                const int* __restrict__ any_flag,
                                const float* __restrict__ child_prev,
                                float* __restrict__ child_next) {
    __shared__ float ELs[JT][KCF];     // 10 KB
    __shared__ float red[4][256];      // 4 KB
    int i = blockIdx.y;
    int hseg = blockIdx.x;
    int t = threadIdx.x;
    int tx = t & 63;
    int ty = t >> 6;                   // 0..3
    int h0 = hseg * 256 + tx * 4;      // 4 h-columns: h0..h0+3

    float w4[4][4];
    #pragma unroll
    for (int tt = 0; tt < 4; ++tt)
        #pragma unroll
        for (int hh = 0; hh < 4; ++hh) w4[tt][hh] = W4[tt * HDIM + h0 + hh];
    float abase[4];
    #pragma unroll
    for (int hh = 0; hh < 4; ++hh) abase[hh] = Abuf[i * HDIM + h0 + hh];
    bool oki = node_ok[i] != 0;
    float osum[4] = {0.f, 0.f, 0.f, 0.f};

    for (int jc = 0; jc < 5; ++jc) {          // j = jc*20 + 0..19
        float acc[5][4];
        #pragma unroll
        for (int jr = 0; jr < 5; ++jr)
            #pragma unroll
            for (int hh = 0; hh < 4; ++hh) acc[jr][hh] = 0.f;

        for (int kc = 0; kc < HDIM; kc += KCF) {
            __syncthreads();
            #pragma unroll
            for (int s = 0; s < 10; ++s) {            // 20*128 = 2560 = 10*256
                int idx = t + s * 256;
                int jr = idx >> 7;                    // 0..19
                int kk = idx & 127;
                int j = jc * JT + jr;                 // <= 99
                ELs[jr][kk] = fmaxf(Xi[i * HDIM + kc + kk] + Xj[j * HDIM + kc + kk], 0.f);
            }
            __syncthreads();
            for (int kk = 0; kk < KCF; ++kk) {
                float4 w = *(const float4*)(W3 + (size_t)(kc + kk) * HDIM + h0);
                #pragma unroll
                for (int jr = 0; jr < 5; ++jr) {
                    float e = ELs[ty * 5 + jr][kk];
                    acc[jr][0] += e * w.x; acc[jr][1] += e * w.y;
                    acc[jr][2] += e * w.z; acc[jr][3] += e * w.w;
                }
            }
        }
        // epilogue: mask + relu + accumulate over this chunk's j
        #pragma unroll
        for (int jr = 0; jr < 5; ++jr) {
            int j = jc * JT + ty * 5 + jr;
            bool okj = node_ok[j] != 0;
            const float* lgp = &elog[(i * M_NODES + j) * 4];
            float s0[4];
            #pragma unroll
            for (int hh = 0; hh < 4; ++hh)
                s0[hh] = abase[hh] + Bbuf[j * HDIM + h0 + hh] + acc[jr][hh];
            #pragma unroll
            for (int tt = 0; tt < 4; ++tt) {
                float lg = lgp[tt];
                if (oki && okj && lg > 0.f) {
                    #pragma unroll
                    for (int hh = 0; hh < 4; ++hh)
                        osum[hh] += fmaxf(s0[hh] + lg * w4[tt][hh], 0.f);
                }
            }
        }
    }
    // reduce the 4 ty-partials
    __syncthreads();
    #pragma unroll
    for (int hh = 0; hh < 4; ++hh) red[ty][tx * 4 + hh] = osum[hh];
    __syncthreads();
    if (ty == 0) {
        int use_new = *any_flag;
        #pragma unroll
        for (int hh = 0; hh < 4; ++hh) {
            float tot = red[0][tx * 4 + hh] + red[1][tx * 4 + hh]
                      + red[2][tx * 4 + hh] + red[3][tx * 4 + hh];
            int idx = i * HDIM + h0 + hh;
            child_next[idx] = use_new ? tot : child_prev[idx];
        }
    }
}

// assemble outputs -> f32 (reference output dtype is float32)
__global__ void cast_kernel(const float* __restrict__ childout, const float* __restrict__ sem,
                            const float* __restrict__ exists, const float* __restrict__ elog,
                            float* __restrict__ out) {
    int id = blockIdx.x * 256 + threadIdx.x;
    if (id >= 97000) return;
    float v;
    if (id < 51200)       v = childout[id];
    else if (id < 56900)  v = sem[id - 51200];
    else if (id < 57000)  v = exists[id - 56900];
    else                  v = elog[id - 57000];
    out[id] = v;
}

extern "C" void kernel_launch(void* const* d_in, const int* in_sizes, int n_in,
                              void* d_out, int out_size, void* d_ws, size_t ws_size,
                              hipStream_t stream) {
    const float* parent   = (const float*)d_in[0];
    const float* W_parent = (const float*)d_in[1];
    const float* b_parent = (const float*)d_in[2];
    const float* W_exists = (const float*)d_in[3];
    const float* b_exists = (const float*)d_in[4];
    const float* W_el     = (const float*)d_in[5];
    const float* b_el     = (const float*)d_in[6];
    const float* W_ee     = (const float*)d_in[7];
    const float* b_ee     = (const float*)d_in[8];
    const float* W_ne     = (const float*)d_in[9];
    const float* b_ne     = (const float*)d_in[10];
    const float* W_child  = (const float*)d_in[11];
    const float* b_child  = (const float*)d_in[12];
    const float* W_sem    = (const float*)d_in[13];
    const float* b_sem    = (const float*)d_in[14];
    const float* W_child2 = (const float*)d_in[15];
    const float* b_child2 = (const float*)d_in[16];
    float* out = (float*)d_out;

    // minimal workspace: ~1.8 MB
    float* ws = (float*)d_ws;
    float* child_bufs = ws;                    // 3 * 51200
    float* Xi       = ws + 3 * MH;             // 51200
    float* Xj       = Xi + MH;                 // 51200
    float* Abuf     = Xj + MH;                 // 51200
    float* Bbuf     = Abuf + MH;               // 51200
    float* elog     = Bbuf + MH;               // 40000
    float* exists   = elog + 40000;            // 100
    int*   node_ok  = (int*)(exists + 100);    // 100
    int*   flag     = node_ok + M_NODES;       // 1
    // aliases (lifetimes verified: Xi/Xj/Abuf dead after msg iterations)
    float* hbuf     = Xi;
    float* sembuf   = Xj;
    float* childout = Abuf;

    const size_t WNE_IT = 1540 * 512;          // W_ne per-iteration stride

    hipMemsetAsync(flag, 0, sizeof(int), stream);

    // 1. child0
    child_kernel<<<200, 256, 0, stream>>>(parent, W_parent, b_parent, child_bufs);

    // 2. exists logits + node_ok
    exists_kernel<<<M_NODES, 256, 0, stream>>>(child_bufs, W_exists, b_exists, exists, node_ok);

    // 3. Xi = child0 @ W_el[:512] + b_el ; Xj = child0 @ W_el[512:]
    gemm_kernel<4><<<dim3(2, 25), 256, 0, stream>>>(child_bufs, W_el, b_el, Xi, M_NODES, 512, 512, 0, 0);
    gemm_kernel<4><<<dim3(2, 25), 256, 0, stream>>>(child_bufs, W_el + 512 * 512, nullptr, Xj, M_NODES, 512, 512, 0, 0);

    // 4. edge_exists_logits + any_edge flag
    elog_kernel<<<MM2, 512, 0, stream>>>(Xi, Xj, W_ee, b_ee, node_ok, elog, flag);

    // 5. message-passing iterations (fully fused, no Cbuf)
    for (int it = 0; it < 2; ++it) {
        const float* cprev = child_bufs + it * MH;
        float* cnext = child_bufs + (it + 1) * MH;
        gemm_kernel<4><<<dim3(2, 25), 256, 0, stream>>>(
            cprev, W_ne + it * WNE_IT, b_ne + it * 512, Abuf, M_NODES, 512, 512, 0, 0);
        gemm_kernel<4><<<dim3(2, 25), 256, 0, stream>>>(
            cprev, W_ne + it * WNE_IT + 512 * 512, nullptr, Bbuf, M_NODES, 512, 512, 0, 0);
        msgfused_kernel<<<dim3(2, M_NODES), 256, 0, stream>>>(
            Xi, Xj, Abuf, Bbuf,
            W_ne + it * WNE_IT + 1024 * 512,   // W3
            W_ne + it * WNE_IT + 1536 * 512,   // W4
            elog, node_ok, flag, cprev, cnext);
    }

    // 6. heads (perm=1 reads hcat layout directly from child_bufs)
    gemm_kernel<4><<<dim3(2, 25), 256, 0, stream>>>(child_bufs, W_child, b_child, hbuf, M_NODES, 512, 1536, 1, 1);
    gemm_kernel<4><<<dim3(1, 25), 256, 0, stream>>>(hbuf, W_sem, b_sem, sembuf, M_NODES, 57, 512, 0, 0);
    gemm_kernel<4><<<dim3(2, 25), 256, 0, stream>>>(hbuf, W_child2, b_child2, childout, M_NODES, 512, 512, 1, 0);

    // 7. assemble f32 output
    cast_kernel<<<380, 256, 0, stream>>>(childout, sembuf, exists, elog, out);
}

// Round 6
// 814.283 us; speedup vs baseline: 2.1570x; 2.1570x over previous
//
#include <hip/hip_runtime.h>

#define M_NODES 100
#define HDIM 512
#define MH (M_NODES*HDIM)       // 51200
#define MM2 (M_NODES*M_NODES)   // 10000

// child = relu(parent @ W_parent + b_parent)  -> [100,512] flattened [51200]
__global__ void child_kernel(const float* __restrict__ parent, const float* __restrict__ Wp,
                             const float* __restrict__ bp, float* __restrict__ child0) {
    __shared__ float p[HDIM];
    int tid = threadIdx.x;
    for (int i = tid; i < HDIM; i += 256) p[i] = parent[i];
    __syncthreads();
    int o = blockIdx.x * 256 + tid;            // < 51200
    float acc = bp[o];
    #pragma unroll 16
    for (int k = 0; k < HDIM; ++k) acc += p[k] * Wp[(size_t)k * MH + o];
    child0[o] = fmaxf(acc, 0.f);
}

// exists_logits[m] = child0[m,:] . W_exists + b_exists ; one wave per m
__global__ void exists_kernel(const float* __restrict__ child0, const float* __restrict__ Wex,
                              const float* __restrict__ bex, float* __restrict__ exists,
                              int* __restrict__ node_ok) {
    int wid = threadIdx.x >> 6, lane = threadIdx.x & 63;
    int m = blockIdx.x * 4 + wid;              // grid 25 -> m < 100
    float s = 0.f;
    #pragma unroll
    for (int k = lane; k < HDIM; k += 64) s += child0[m * HDIM + k] * Wex[k];
    #pragma unroll
    for (int off = 32; off; off >>= 1) s += __shfl_down(s, off);
    if (lane == 0) {
        float v = s + bex[0];
        exists[m] = v;
        node_ok[m] = (v > 0.f) ? 1 : 0;
    }
}

// Single GEMM (used for the perm'd W_child head):
// C[m,n] = (relu?)(sum_k A[m,k]*B[k,n] + bias[n]); perm: A[m,k]=Abase[(k>>9)*MH+m*512+(k&511)]
template<int TM>
__global__ void gemm_kernel(const float* __restrict__ A, const float* __restrict__ B,
                            const float* __restrict__ bias, float* __restrict__ C,
                            int M, int N, int K, int do_relu, int perm) {
    const int KC = 256;
    __shared__ float As[TM][KC];
    int n = blockIdx.x * 256 + threadIdx.x;
    int m0 = blockIdx.y * TM;
    float acc[TM];
    #pragma unroll
    for (int mm = 0; mm < TM; ++mm) acc[mm] = 0.f;
    for (int kc = 0; kc < K; kc += KC) {
        for (int idx = threadIdx.x; idx < TM * KC; idx += 256) {
            int mm = idx / KC, kk = idx % KC;
            int m = m0 + mm;
            float av = 0.f;
            if (m < M) {
                int k = kc + kk;
                av = perm ? A[(k >> 9) * MH + m * HDIM + (k & 511)]
                          : A[(size_t)m * K + k];
            }
            As[mm][kk] = av;
        }
        __syncthreads();
        if (n < N) {
            for (int kk = 0; kk < KC; ++kk) {
                float bv = B[(size_t)(kc + kk) * N + n];
                #pragma unroll
                for (int mm = 0; mm < TM; ++mm) acc[mm] += As[mm][kk] * bv;
            }
        }
        __syncthreads();
    }
    if (n < N) {
        float bs = bias ? bias[n] : 0.f;
        #pragma unroll
        for (int mm = 0; mm < TM; ++mm) {
            int m = m0 + mm;
            if (m < M) {
                float v = acc[mm] + bs;
                if (do_relu) v = fmaxf(v, 0.f);
                C[(size_t)m * N + n] = v;
            }
        }
    }
}

// Dual GEMM: shared A [100,K]; side1: C1[m,n]=A@B1+bias1 (N1 cols), side2 likewise.
// grid: (ceil((N1+N2)/256), 25), block 256. K multiple of 256. TM=4 rows/block.
template<int TM>
__global__ void dual_gemm(const float* __restrict__ A, int K,
                          const float* __restrict__ B1, const float* __restrict__ bias1,
                          int relu1, float* __restrict__ C1, int N1,
                          const float* __restrict__ B2, const float* __restrict__ bias2,
                          int relu2, float* __restrict__ C2, int N2) {
    const int KC = 256;
    __shared__ float As[TM][KC];
    int n = blockIdx.x * 256 + threadIdx.x;
    int m0 = blockIdx.y * TM;
    bool second = n >= N1;
    int nn = second ? n - N1 : n;
    const float* B = second ? B2 : B1;
    int NN = second ? N2 : N1;
    bool valid = nn < NN;
    float acc[TM];
    #pragma unroll
    for (int mm = 0; mm < TM; ++mm) acc[mm] = 0.f;
    for (int kc = 0; kc < K; kc += KC) {
        for (int idx = threadIdx.x; idx < TM * KC; idx += 256) {
            int mm = idx / KC, kk = idx % KC;
            As[mm][kk] = A[(size_t)(m0 + mm) * K + kc + kk];
        }
        __syncthreads();
        if (valid) {
            for (int kk = 0; kk < KC; ++kk) {
                float bv = B[(size_t)(kc + kk) * NN + nn];
                #pragma unroll
                for (int mm = 0; mm < TM; ++mm) acc[mm] += As[mm][kk] * bv;
            }
        }
        __syncthreads();
    }
    if (valid) {
        const float* bias = second ? bias2 : bias1;
        int do_relu = second ? relu2 : relu1;
        float* C = second ? C2 : C1;
        float bs = bias ? bias[nn] : 0.f;
        #pragma unroll
        for (int mm = 0; mm < TM; ++mm) {
            float v = acc[mm] + bs;
            if (do_relu) v = fmaxf(v, 0.f);
            C[(size_t)(m0 + mm) * NN + nn] = v;
        }
    }
}

// elog[i,j,t] = relu(Xi[i]+Xj[j]) . W_ee[t] + b_ee[t] ; one wave per (i,j) pair
__global__ void elog_kernel(const float* __restrict__ Xi, const float* __restrict__ Xj,
                            const float* __restrict__ Wee, const float* __restrict__ bee,
                            const int* __restrict__ node_ok,
                            float* __restrict__ elog, int* __restrict__ any_flag) {
    int wid = threadIdx.x >> 6, lane = threadIdx.x & 63;
    int pair = blockIdx.x * 4 + wid;           // grid 2500 -> pair < 10000
    int i = pair / M_NODES, j = pair - (pair / M_NODES) * M_NODES;
    float s0 = 0.f, s1 = 0.f, s2 = 0.f, s3 = 0.f;
    #pragma unroll
    for (int k = lane; k < HDIM; k += 64) {
        float v = fmaxf(Xi[i * HDIM + k] + Xj[j * HDIM + k], 0.f);
        s0 += v * Wee[k];          s1 += v * Wee[HDIM + k];
        s2 += v * Wee[2*HDIM + k]; s3 += v * Wee[3*HDIM + k];
    }
    #pragma unroll
    for (int off = 32; off; off >>= 1) {
        s0 += __shfl_down(s0, off); s1 += __shfl_down(s1, off);
        s2 += __shfl_down(s2, off); s3 += __shfl_down(s3, off);
    }
    if (lane == 0) {
        bool ok = node_ok[i] && node_ok[j];
        float lg0 = s0 + bee[0], lg1 = s1 + bee[1], lg2 = s2 + bee[2], lg3 = s3 + bee[3];
        elog[pair * 4 + 0] = lg0; elog[pair * 4 + 1] = lg1;
        elog[pair * 4 + 2] = lg2; elog[pair * 4 + 3] = lg3;
        bool any = ok && (lg0 > 0.f || lg1 > 0.f || lg2 > 0.f || lg3 > 0.f);
        if (any && *(volatile int*)any_flag == 0) atomicOr(any_flag, 1);
    }
}

// Partial fused message step: block (hseg, i, jc) covers 20 j's.
//   partial[jc][i][h] = sum_{j in chunk, t} mask[i,j,t]*relu(A[i,h]+B[j,h]+C[i,j,h]+lg*W4[t,h])
//   with C[i,j,h] = sum_k relu(Xi[i,k]+Xj[j,k]) * W3[k,h]  (never materialized)
// grid: dim3(2, 100, 5), block 256. tx = t&63 owns h-quad, ty = t>>6 covers 5 j's.
#define JT 20
#define KCF 128
__global__ void msgfused_kernel(const float* __restrict__ Xi, const float* __restrict__ Xj,
                                const float* __restrict__ Abuf, const float* __restrict__ Bbuf,
                                const float* __restrict__ W3, const float* __restrict__ W4,
                                const float* __restrict__ elog, const int* __restrict__ node_ok,
                                float* __restrict__ partial) {
    __shared__ float ELs[JT][KCF];     // 10 KB
    __shared__ float red[4][256];      // 4 KB
    int i = blockIdx.y;
    int hseg = blockIdx.x;
    int jc = blockIdx.z;
    int t = threadIdx.x;
    int tx = t & 63;
    int ty = t >> 6;                   // 0..3
    int h0 = hseg * 256 + tx * 4;      // 4 h-columns: h0..h0+3

    float w4[4][4];
    #pragma unroll
    for (int tt = 0; tt < 4; ++tt)
        #pragma unroll
        for (int hh = 0; hh < 4; ++hh) w4[tt][hh] = W4[tt * HDIM + h0 + hh];
    float abase[4];
    #pragma unroll
    for (int hh = 0; hh < 4; ++hh) abase[hh] = Abuf[i * HDIM + h0 + hh];
    bool oki = node_ok[i] != 0;

    float acc[5][4];
    #pragma unroll
    for (int jr = 0; jr < 5; ++jr)
        #pragma unroll
        for (int hh = 0; hh < 4; ++hh) acc[jr][hh] = 0.f;

    for (int kc = 0; kc < HDIM; kc += KCF) {
        __syncthreads();
        #pragma unroll
        for (int s = 0; s < 10; ++s) {            // 20*128 = 2560 = 10*256
            int idx = t + s * 256;
            int jr = idx >> 7;                    // 0..19
            int kk = idx & 127;
            int j = jc * JT + jr;                 // <= 99
            ELs[jr][kk] = fmaxf(Xi[i * HDIM + kc + kk] + Xj[j * HDIM + kc + kk], 0.f);
        }
        __syncthreads();
        for (int kk = 0; kk < KCF; ++kk) {
            float4 w = *(const float4*)(W3 + (size_t)(kc + kk) * HDIM + h0);
            #pragma unroll
            for (int jr = 0; jr < 5; ++jr) {
                float e = ELs[ty * 5 + jr][kk];
                acc[jr][0] += e * w.x; acc[jr][1] += e * w.y;
                acc[jr][2] += e * w.z; acc[jr][3] += e * w.w;
            }
        }
    }
    // epilogue: mask + relu + accumulate over this chunk's j
    float osum[4] = {0.f, 0.f, 0.f, 0.f};
    #pragma unroll
    for (int jr = 0; jr < 5; ++jr) {
        int j = jc * JT + ty * 5 + jr;
        bool okj = node_ok[j] != 0;
        const float* lgp = &elog[(i * M_NODES + j) * 4];
        float s0[4];
        #pragma unroll
        for (int hh = 0; hh < 4; ++hh)
            s0[hh] = abase[hh] + Bbuf[j * HDIM + h0 + hh] + acc[jr][hh];
        #pragma unroll
        for (int tt = 0; tt < 4; ++tt) {
            float lg = lgp[tt];
            if (oki && okj && lg > 0.f) {
                #pragma unroll
                for (int hh = 0; hh < 4; ++hh)
                    osum[hh] += fmaxf(s0[hh] + lg * w4[tt][hh], 0.f);
            }
        }
    }
    // reduce the 4 ty-partials, write this jc's partial
    __syncthreads();
    #pragma unroll
    for (int hh = 0; hh < 4; ++hh) red[ty][tx * 4 + hh] = osum[hh];
    __syncthreads();
    if (ty == 0) {
        #pragma unroll
        for (int hh = 0; hh < 4; ++hh) {
            float tot = red[0][tx * 4 + hh] + red[1][tx * 4 + hh]
                      + red[2][tx * 4 + hh] + red[3][tx * 4 + hh];
            partial[jc * MH + i * HDIM + h0 + hh] = tot;
        }
    }
}

// fold 5 jc-partials + any_edge select
__global__ void msgreduce_kernel(const float* __restrict__ partial,
                                 const float* __restrict__ child_prev,
                                 float* __restrict__ child_next,
                                 const int* __restrict__ any_flag) {
    int id = blockIdx.x * 256 + threadIdx.x;   // grid 200 -> id < 51200
    float s = 0.f;
    #pragma unroll
    for (int jc = 0; jc < 5; ++jc) s += partial[jc * MH + id];
    child_next[id] = (*any_flag) ? s : child_prev[id];
}

// assemble outputs -> f32 (reference output dtype is float32)
__global__ void cast_kernel(const float* __restrict__ childout, const float* __restrict__ sem,
                            const float* __restrict__ exists, const float* __restrict__ elog,
                            float* __restrict__ out) {
    int id = blockIdx.x * 256 + threadIdx.x;
    if (id >= 97000) return;
    float v;
    if (id < 51200)       v = childout[id];
    else if (id < 56900)  v = sem[id - 51200];
    else if (id < 57000)  v = exists[id - 56900];
    else                  v = elog[id - 57000];
    out[id] = v;
}

extern "C" void kernel_launch(void* const* d_in, const int* in_sizes, int n_in,
                              void* d_out, int out_size, void* d_ws, size_t ws_size,
                              hipStream_t stream) {
    const float* parent   = (const float*)d_in[0];
    const float* W_parent = (const float*)d_in[1];
    const float* b_parent = (const float*)d_in[2];
    const float* W_exists = (const float*)d_in[3];
    const float* b_exists = (const float*)d_in[4];
    const float* W_el     = (const float*)d_in[5];
    const float* b_el     = (const float*)d_in[6];
    const float* W_ee     = (const float*)d_in[7];
    const float* b_ee     = (const float*)d_in[8];
    const float* W_ne     = (const float*)d_in[9];
    const float* b_ne     = (const float*)d_in[10];
    const float* W_child  = (const float*)d_in[11];
    const float* b_child  = (const float*)d_in[12];
    const float* W_sem    = (const float*)d_in[13];
    const float* b_sem    = (const float*)d_in[14];
    const float* W_child2 = (const float*)d_in[15];
    const float* b_child2 = (const float*)d_in[16];
    float* out = (float*)d_out;

    // workspace: ~2.8 MB
    float* ws = (float*)d_ws;
    float* child_bufs = ws;                    // 3 * 51200
    float* Xi       = ws + 3 * MH;             // 51200
    float* Xj       = Xi + MH;                 // 51200
    float* Abuf     = Xj + MH;                 // 51200
    float* Bbuf     = Abuf + MH;               // 51200
    float* elog     = Bbuf + MH;               // 40000
    float* exists   = elog + 40000;            // 100
    int*   node_ok  = (int*)(exists + 100);    // 100
    int*   flag     = node_ok + M_NODES;       // 1
    float* partial  = (float*)(flag + 1);      // 5 * 51200
    // aliases (lifetimes: Xi/Xj/Abuf dead after msg iterations)
    float* hbuf     = Xi;
    float* sembuf   = Xj;
    float* childout = Abuf;

    const size_t WNE_IT = 1540 * 512;          // W_ne per-iteration stride

    hipMemsetAsync(flag, 0, sizeof(int), stream);

    // 1. child0
    child_kernel<<<200, 256, 0, stream>>>(parent, W_parent, b_parent, child_bufs);

    // 2. exists logits + node_ok
    exists_kernel<<<25, 256, 0, stream>>>(child_bufs, W_exists, b_exists, exists, node_ok);

    // 3. Xi = child0 @ W_el[:512] + b_el ; Xj = child0 @ W_el[512:]  (one launch)
    dual_gemm<4><<<dim3(4, 25), 256, 0, stream>>>(
        child_bufs, 512, W_el, b_el, 0, Xi, 512,
        W_el + 512 * 512, nullptr, 0, Xj, 512);

    // 4. edge_exists_logits + any_edge flag (wave per pair)
    elog_kernel<<<2500, 256, 0, stream>>>(Xi, Xj, W_ee, b_ee, node_ok, elog, flag);

    // 5. message-passing iterations (split-j fused GEMM + reduce)
    for (int it = 0; it < 2; ++it) {
        const float* cprev = child_bufs + it * MH;
        float* cnext = child_bufs + (it + 1) * MH;
        dual_gemm<4><<<dim3(4, 25), 256, 0, stream>>>(
            cprev, 512, W_ne + it * WNE_IT, b_ne + it * 512, 0, Abuf, 512,
            W_ne + it * WNE_IT + 512 * 512, nullptr, 0, Bbuf, 512);
        msgfused_kernel<<<dim3(2, M_NODES, 5), 256, 0, stream>>>(
            Xi, Xj, Abuf, Bbuf,
            W_ne + it * WNE_IT + 1024 * 512,   // W3
            W_ne + it * WNE_IT + 1536 * 512,   // W4
            elog, node_ok, partial);
        msgreduce_kernel<<<200, 256, 0, stream>>>(partial, cprev, cnext, flag);
    }

    // 6. heads
    gemm_kernel<4><<<dim3(2, 25), 256, 0, stream>>>(child_bufs, W_child, b_child, hbuf,
                                                    M_NODES, 512, 1536, 1, 1);
    dual_gemm<4><<<dim3(3, 25), 256, 0, stream>>>(
        hbuf, 512, W_child2, b_child2, 1, childout, 512,
        W_sem, b_sem, 0, sembuf, 57);

    // 7. assemble f32 output
    cast_kernel<<<380, 256, 0, stream>>>(childout, sembuf, exists, elog, out);
}

// Round 7
// 526.608 us; speedup vs baseline: 3.3353x; 1.5463x over previous
//
#include <hip/hip_runtime.h>

#define M_NODES 100
#define HDIM 512
#define MH (M_NODES*HDIM)       // 51200
#define MM2 (M_NODES*M_NODES)   // 10000

// ---- child = relu(parent @ W_parent + b_parent), split-K ----
// grid (200, 4), block 256. partial_c[ky][o] = sum over 128-k range.
__global__ void child_spk(const float* __restrict__ parent, const float* __restrict__ Wp,
                          float* __restrict__ partial_c) {
    __shared__ float p[128];
    int t = threadIdx.x;
    int kc = blockIdx.y * 128;
    if (t < 128) p[t] = parent[kc + t];
    __syncthreads();
    int o = blockIdx.x * 256 + t;              // < 51200
    float acc = 0.f;
    #pragma unroll 8
    for (int k = 0; k < 128; ++k) acc += p[k] * Wp[(size_t)(kc + k) * MH + o];
    partial_c[blockIdx.y * MH + o] = acc;
}

__global__ void child_reduce(const float* __restrict__ partial_c, const float* __restrict__ bp,
                             float* __restrict__ child0) {
    int o = blockIdx.x * 256 + threadIdx.x;
    float s = bp[o];
    #pragma unroll
    for (int q = 0; q < 4; ++q) s += partial_c[q * MH + o];
    child0[o] = fmaxf(s, 0.f);
}

// exists_logits[m] = child0[m,:] . W_exists + b_exists ; one wave per m
__global__ void exists_kernel(const float* __restrict__ child0, const float* __restrict__ Wex,
                              const float* __restrict__ bex, float* __restrict__ exists,
                              int* __restrict__ node_ok) {
    int wid = threadIdx.x >> 6, lane = threadIdx.x & 63;
    int m = blockIdx.x * 4 + wid;              // grid 25 -> m < 100
    float s = 0.f;
    #pragma unroll
    for (int k = lane; k < HDIM; k += 64) s += child0[m * HDIM + k] * Wex[k];
    #pragma unroll
    for (int off = 32; off; off >>= 1) s += __shfl_down(s, off);
    if (lane == 0) {
        float v = s + bex[0];
        exists[m] = v;
        node_ok[m] = (v > 0.f) ? 1 : 0;
    }
}

// ---- split-K GEMM partials ----
// grid (col_tiles, 25, K/256), block 256. Block: 4 rows x 64 cols x 256-k chunk.
// partial[kchunk][m][col] = sum_k A[m,k]*B[k,col]  (dual-B: col<N1 -> B1, else B2)
// PERM: A[m,k] = A[(k>>9)*MH + m*512 + (k&511)]  (hcat layout)
template<int PERM>
__global__ void spk_gemm(const float* __restrict__ A, int K,
                         const float* __restrict__ B1, int N1,
                         const float* __restrict__ B2, int N2,
                         float* __restrict__ partial) {
    __shared__ float As[4][256];
    int t = threadIdx.x;
    int NT = N1 + N2;
    int m0 = blockIdx.y * 4;
    int kc = blockIdx.z * 256;
    {   // A tile: thread t -> row t>>6, 4 k's at (t&63)*4
        int row = t >> 6, c4 = (t & 63) * 4;
        int m = m0 + row, k = kc + c4;
        float4 a = PERM ? *(const float4*)(A + (k >> 9) * MH + m * HDIM + (k & 511))
                        : *(const float4*)(A + (size_t)m * K + k);
        *(float4*)&As[row][c4] = a;
    }
    __syncthreads();
    int col = blockIdx.x * 64 + (t & 63);
    int row = t >> 6;
    int m = m0 + row;
    if (col >= NT) return;
    bool second = col >= N1;
    const float* B = second ? B2 : B1;
    int nn = second ? col - N1 : col;
    int NN = second ? N2 : N1;
    float acc = 0.f;
    const float* bp = B + (size_t)kc * NN + nn;
    #pragma unroll 8
    for (int kk = 0; kk < 256; ++kk) acc += As[row][kk] * bp[(size_t)kk * NN];
    partial[((size_t)blockIdx.z * M_NODES + m) * NT + col] = acc;
}

// fold k_chunks partials + bias + optional relu; dual outputs split at N1
__global__ void spk_reduce(const float* __restrict__ partial, int k_chunks,
                           const float* __restrict__ bias1, int relu1,
                           float* __restrict__ C1, int N1,
                           const float* __restrict__ bias2, int relu2,
                           float* __restrict__ C2, int N2) {
    int NT = N1 + N2;
    int id = blockIdx.x * 256 + threadIdx.x;
    if (id >= M_NODES * NT) return;
    int m = id / NT, col = id - m * NT;
    float s = 0.f;
    for (int kc = 0; kc < k_chunks; ++kc)
        s += partial[((size_t)kc * M_NODES + m) * NT + col];
    if (col < N1) {
        s += bias1 ? bias1[col] : 0.f;
        if (relu1) s = fmaxf(s, 0.f);
        C1[(size_t)m * N1 + col] = s;
    } else {
        int nn = col - N1;
        s += bias2 ? bias2[nn] : 0.f;
        if (relu2) s = fmaxf(s, 0.f);
        C2[(size_t)m * N2 + nn] = s;
    }
}

// elog[i,j,t] = relu(Xi[i]+Xj[j]) . W_ee[t] + b_ee[t] ; one wave per (i,j) pair
__global__ void elog_kernel(const float* __restrict__ Xi, const float* __restrict__ Xj,
                            const float* __restrict__ Wee, const float* __restrict__ bee,
                            const int* __restrict__ node_ok,
                            float* __restrict__ elog, int* __restrict__ any_flag) {
    int wid = threadIdx.x >> 6, lane = threadIdx.x & 63;
    int pair = blockIdx.x * 4 + wid;           // grid 2500 -> pair < 10000
    int i = pair / M_NODES, j = pair - (pair / M_NODES) * M_NODES;
    float s0 = 0.f, s1 = 0.f, s2 = 0.f, s3 = 0.f;
    #pragma unroll
    for (int k = lane; k < HDIM; k += 64) {
        float v = fmaxf(Xi[i * HDIM + k] + Xj[j * HDIM + k], 0.f);
        s0 += v * Wee[k];          s1 += v * Wee[HDIM + k];
        s2 += v * Wee[2*HDIM + k]; s3 += v * Wee[3*HDIM + k];
    }
    #pragma unroll
    for (int off = 32; off; off >>= 1) {
        s0 += __shfl_down(s0, off); s1 += __shfl_down(s1, off);
        s2 += __shfl_down(s2, off); s3 += __shfl_down(s3, off);
    }
    if (lane == 0) {
        bool ok = node_ok[i] && node_ok[j];
        float lg0 = s0 + bee[0], lg1 = s1 + bee[1], lg2 = s2 + bee[2], lg3 = s3 + bee[3];
        elog[pair * 4 + 0] = lg0; elog[pair * 4 + 1] = lg1;
        elog[pair * 4 + 2] = lg2; elog[pair * 4 + 3] = lg3;
        bool any = ok && (lg0 > 0.f || lg1 > 0.f || lg2 > 0.f || lg3 > 0.f);
        if (any && *(volatile int*)any_flag == 0) atomicOr(any_flag, 1);
    }
}

// Partial fused message step: block (hseg, i, jc) covers 20 j's.
//   partial[jc][i][h] = sum_{j in chunk, t} mask[i,j,t]*relu(A[i,h]+B[j,h]+C[i,j,h]+lg*W4[t,h])
//   with C[i,j,h] = sum_k relu(Xi[i,k]+Xj[j,k]) * W3[k,h]  (never materialized)
// grid: dim3(2, 100, 5), block 256. tx = t&63 owns h-quad, ty = t>>6 covers 5 j's.
#define JT 20
#define KCF 128
__global__ void msgfused_kernel(const float* __restrict__ Xi, const float* __restrict__ Xj,
                                const float* __restrict__ Abuf, const float* __restrict__ Bbuf,
                                const float* __restrict__ W3, const float* __restrict__ W4,
                                const float* __restrict__ elog, const int* __restrict__ node_ok,
                                float* __restrict__ partial) {
    __shared__ float ELs[JT][KCF];     // 10 KB
    __shared__ float red[4][256];      // 4 KB
    int i = blockIdx.y;
    int hseg = blockIdx.x;
    int jc = blockIdx.z;
    int t = threadIdx.x;
    int tx = t & 63;
    int ty = t >> 6;                   // 0..3
    int h0 = hseg * 256 + tx * 4;      // 4 h-columns: h0..h0+3

    float w4[4][4];
    #pragma unroll
    for (int tt = 0; tt < 4; ++tt)
        #pragma unroll
        for (int hh = 0; hh < 4; ++hh) w4[tt][hh] = W4[tt * HDIM + h0 + hh];
    float abase[4];
    #pragma unroll
    for (int hh = 0; hh < 4; ++hh) abase[hh] = Abuf[i * HDIM + h0 + hh];
    bool oki = node_ok[i] != 0;

    float acc[5][4];
    #pragma unroll
    for (int jr = 0; jr < 5; ++jr)
        #pragma unroll
        for (int hh = 0; hh < 4; ++hh) acc[jr][hh] = 0.f;

    for (int kc = 0; kc < HDIM; kc += KCF) {
        __syncthreads();
        #pragma unroll
        for (int s = 0; s < 10; ++s) {            // 20*128 = 2560 = 10*256
            int idx = t + s * 256;
            int jr = idx >> 7;                    // 0..19
            int kk = idx & 127;
            int j = jc * JT + jr;                 // <= 99
            ELs[jr][kk] = fmaxf(Xi[i * HDIM + kc + kk] + Xj[j * HDIM + kc + kk], 0.f);
        }
        __syncthreads();
        for (int kk = 0; kk < KCF; kk += 4) {
            float4 w0 = *(const float4*)(W3 + (size_t)(kc + kk + 0) * HDIM + h0);
            float4 w1 = *(const float4*)(W3 + (size_t)(kc + kk + 1) * HDIM + h0);
            float4 w2 = *(const float4*)(W3 + (size_t)(kc + kk + 2) * HDIM + h0);
            float4 w3 = *(const float4*)(W3 + (size_t)(kc + kk + 3) * HDIM + h0);
            #pragma unroll
            for (int jr = 0; jr < 5; ++jr) {
                float4 e = *(const float4*)&ELs[ty * 5 + jr][kk];  // broadcast b128
                acc[jr][0] += e.x*w0.x + e.y*w1.x + e.z*w2.x + e.w*w3.x;
                acc[jr][1] += e.x*w0.y + e.y*w1.y + e.z*w2.y + e.w*w3.y;
                acc[jr][2] += e.x*w0.z + e.y*w1.z + e.z*w2.z + e.w*w3.z;
                acc[jr][3] += e.x*w0.w + e.y*w1.w + e.z*w2.w + e.w*w3.w;
            }
        }
    }
    // epilogue: mask + relu + accumulate over this chunk's j
    float osum[4] = {0.f, 0.f, 0.f, 0.f};
    #pragma unroll
    for (int jr = 0; jr < 5; ++jr) {
        int j = jc * JT + ty * 5 + jr;
        bool okj = node_ok[j] != 0;
        const float* lgp = &elog[(i * M_NODES + j) * 4];
        float s0[4];
        #pragma unroll
        for (int hh = 0; hh < 4; ++hh)
            s0[hh] = abase[hh] + Bbuf[j * HDIM + h0 + hh] + acc[jr][hh];
        #pragma unroll
        for (int tt = 0; tt < 4; ++tt) {
            float lg = lgp[tt];
            if (oki && okj && lg > 0.f) {
                #pragma unroll
                for (int hh = 0; hh < 4; ++hh)
                    osum[hh] += fmaxf(s0[hh] + lg * w4[tt][hh], 0.f);
            }
        }
    }
    // reduce the 4 ty-partials, write this jc's partial
    __syncthreads();
    #pragma unroll
    for (int hh = 0; hh < 4; ++hh) red[ty][tx * 4 + hh] = osum[hh];
    __syncthreads();
    if (ty == 0) {
        #pragma unroll
        for (int hh = 0; hh < 4; ++hh) {
            float tot = red[0][tx * 4 + hh] + red[1][tx * 4 + hh]
                      + red[2][tx * 4 + hh] + red[3][tx * 4 + hh];
            partial[jc * MH + i * HDIM + h0 + hh] = tot;
        }
    }
}

// fold 5 jc-partials + any_edge select
__global__ void msgreduce_kernel(const float* __restrict__ partial,
                                 const float* __restrict__ child_prev,
                                 float* __restrict__ child_next,
                                 const int* __restrict__ any_flag) {
    int id = blockIdx.x * 256 + threadIdx.x;   // grid 200 -> id < 51200
    float s = 0.f;
    #pragma unroll
    for (int jc = 0; jc < 5; ++jc) s += partial[jc * MH + id];
    child_next[id] = (*any_flag) ? s : child_prev[id];
}

// assemble outputs -> f32
__global__ void cast_kernel(const float* __restrict__ childout, const float* __restrict__ sem,
                            const float* __restrict__ exists, const float* __restrict__ elog,
                            float* __restrict__ out) {
    int id = blockIdx.x * 256 + threadIdx.x;
    if (id >= 97000) return;
    float v;
    if (id < 51200)       v = childout[id];
    else if (id < 56900)  v = sem[id - 51200];
    else if (id < 57000)  v = exists[id - 56900];
    else                  v = elog[id - 57000];
    out[id] = v;
}

extern "C" void kernel_launch(void* const* d_in, const int* in_sizes, int n_in,
                              void* d_out, int out_size, void* d_ws, size_t ws_size,
                              hipStream_t stream) {
    const float* parent   = (const float*)d_in[0];
    const float* W_parent = (const float*)d_in[1];
    const float* b_parent = (const float*)d_in[2];
    const float* W_exists = (const float*)d_in[3];
    const float* b_exists = (const float*)d_in[4];
    const float* W_el     = (const float*)d_in[5];
    const float* b_el     = (const float*)d_in[6];
    const float* W_ee     = (const float*)d_in[7];
    const float* b_ee     = (const float*)d_in[8];
    const float* W_ne     = (const float*)d_in[9];
    const float* b_ne     = (const float*)d_in[10];
    const float* W_child  = (const float*)d_in[11];
    const float* b_child  = (const float*)d_in[12];
    const float* W_sem    = (const float*)d_in[13];
    const float* b_sem    = (const float*)d_in[14];
    const float* W_child2 = (const float*)d_in[15];
    const float* b_child2 = (const float*)d_in[16];
    float* out = (float*)d_out;

    // workspace: ~3.7 MB
    float* ws = (float*)d_ws;
    float* child_bufs = ws;                    // 3 * 51200
    float* Xi       = ws + 3 * MH;             // 51200
    float* Xj       = Xi + MH;                 // 51200
    float* Abuf     = Xj + MH;                 // 51200
    float* Bbuf     = Abuf + MH;               // 51200
    float* elog     = Bbuf + MH;               // 40000
    float* exists   = elog + 40000;            // 100
    int*   node_ok  = (int*)(exists + 100);    // 100
    int*   flag     = node_ok + M_NODES;       // 1
    float* childpart= (float*)(flag + 1);      // 4 * 51200
    float* scratch  = childpart + 4 * MH;      // 307200 (max split-K / msg partials)
    // aliases (lifetimes: Xi/Xj/Abuf dead after msg iterations)
    float* hbuf     = Xi;
    float* sembuf   = Xj;
    float* childout = Abuf;

    const size_t WNE_IT = 1540 * 512;          // W_ne per-iteration stride

    hipMemsetAsync(flag, 0, sizeof(int), stream);

    // 1. child0 (split-K x4)
    child_spk<<<dim3(200, 4), 256, 0, stream>>>(parent, W_parent, childpart);
    child_reduce<<<200, 256, 0, stream>>>(childpart, b_parent, child_bufs);

    // 2. exists logits + node_ok
    exists_kernel<<<25, 256, 0, stream>>>(child_bufs, W_exists, b_exists, exists, node_ok);

    // 3. Xi | Xj (split-K dual GEMM: NT=1024)
    spk_gemm<0><<<dim3(16, 25, 2), 256, 0, stream>>>(child_bufs, 512,
        W_el, 512, W_el + 512 * 512, 512, scratch);
    spk_reduce<<<400, 256, 0, stream>>>(scratch, 2, b_el, 0, Xi, 512, nullptr, 0, Xj, 512);

    // 4. edge_exists_logits + any_edge flag (wave per pair)
    elog_kernel<<<2500, 256, 0, stream>>>(Xi, Xj, W_ee, b_ee, node_ok, elog, flag);

    // 5. message-passing iterations
    for (int it = 0; it < 2; ++it) {
        const float* cprev = child_bufs + it * MH;
        float* cnext = child_bufs + (it + 1) * MH;
        spk_gemm<0><<<dim3(16, 25, 2), 256, 0, stream>>>(cprev, 512,
            W_ne + it * WNE_IT, 512, W_ne + it * WNE_IT + 512 * 512, 512, scratch);
        spk_reduce<<<400, 256, 0, stream>>>(scratch, 2, b_ne + it * 512, 0, Abuf, 512,
                                            nullptr, 0, Bbuf, 512);
        msgfused_kernel<<<dim3(2, M_NODES, 5), 256, 0, stream>>>(
            Xi, Xj, Abuf, Bbuf,
            W_ne + it * WNE_IT + 1024 * 512,   // W3
            W_ne + it * WNE_IT + 1536 * 512,   // W4
            elog, node_ok, scratch);
        msgreduce_kernel<<<200, 256, 0, stream>>>(scratch, cprev, cnext, flag);
    }

    // 6. heads: hbuf = relu(hcat @ W_child + b) via perm'd split-K (6 chunks)
    spk_gemm<1><<<dim3(8, 25, 6), 256, 0, stream>>>(child_bufs, 1536,
        W_child, 512, nullptr, 0, scratch);
    spk_reduce<<<200, 256, 0, stream>>>(scratch, 6, b_child, 1, hbuf, 512,
                                        nullptr, 0, (float*)nullptr, 0);
    //    child_out | sem (NT=569)
    spk_gemm<0><<<dim3(9, 25, 2), 256, 0, stream>>>(hbuf, 512,
        W_child2, 512, W_sem, 57, scratch);
    spk_reduce<<<223, 256, 0, stream>>>(scratch, 2, b_child2, 1, childout, 512,
                                        b_sem, 0, sembuf, 57);

    // 7. assemble f32 output
    cast_kernel<<<380, 256, 0, stream>>>(childout, sembuf, exists, elog, out);
}

// Round 8
// 434.683 us; speedup vs baseline: 4.0406x; 1.2115x over previous
//
#include <hip/hip_runtime.h>

#define M_NODES 100
#define HDIM 512
#define MH (M_NODES*HDIM)       // 51200
#define MM2 (M_NODES*M_NODES)   // 10000
#define WNE_IT (1540*512)

typedef __attribute__((ext_vector_type(8))) short short8v;   // 8 bf16 (4 VGPRs)
typedef __attribute__((ext_vector_type(4))) float float4v;   // MFMA acc

static __device__ __forceinline__ short f2b(float f) {
    union { float f; unsigned u; } v; v.f = f;
    unsigned r = (v.u + 0x7FFF + ((v.u >> 16) & 1)) >> 16;   // RNE
    return (short)r;
}

// ---- W3 prep: transpose + bf16 convert, both iterations ----
// W3[it][k][h] f32 -> W3t[it][h][k] bf16.  grid (16,16,2), block 256 (32x8).
__global__ void w3prep(const float* __restrict__ W_ne, short* __restrict__ W3t) {
    __shared__ float tile[32][33];
    int it = blockIdx.z, kt = blockIdx.x, ht = blockIdx.y;
    const float* W3 = W_ne + (size_t)it * WNE_IT + 1024 * 512;
    int tx = threadIdx.x & 31, ty = threadIdx.x >> 5;        // ty 0..7
    #pragma unroll
    for (int r = 0; r < 4; ++r) {
        int k = kt * 32 + ty * 4 + r;
        tile[ty * 4 + r][tx] = W3[(size_t)k * 512 + ht * 32 + tx];
    }
    __syncthreads();
    #pragma unroll
    for (int r = 0; r < 4; ++r) {
        int h = ht * 32 + ty * 4 + r;
        W3t[(size_t)it * 262144 + (size_t)h * 512 + kt * 32 + tx] = f2b(tile[tx][ty * 4 + r]);
    }
}

// ---- child = relu(parent @ W_parent + b_parent), split-K x8, float4 ----
__global__ void child_spk(const float* __restrict__ parent, const float* __restrict__ Wp,
                          float* __restrict__ partial_c) {
    __shared__ float p[64];
    int t = threadIdx.x;
    int kc = blockIdx.y * 64;
    if (t < 64) p[t] = parent[kc + t];
    __syncthreads();
    int o4 = (blockIdx.x * 256 + t) * 4;       // < 51200
    float4 acc = make_float4(0.f, 0.f, 0.f, 0.f);
    #pragma unroll 4
    for (int k = 0; k < 64; ++k) {
        float4 w = *(const float4*)(Wp + (size_t)(kc + k) * MH + o4);
        float pv = p[k];
        acc.x += pv * w.x; acc.y += pv * w.y; acc.z += pv * w.z; acc.w += pv * w.w;
    }
    *(float4*)(partial_c + (size_t)blockIdx.y * MH + o4) = acc;
}

__global__ void child_reduce(const float* __restrict__ partial_c, const float* __restrict__ bp,
                             float* __restrict__ child0) {
    int o4 = (blockIdx.x * 256 + threadIdx.x) * 4;
    float4 s = *(const float4*)(bp + o4);
    #pragma unroll
    for (int q = 0; q < 8; ++q) {
        float4 v = *(const float4*)(partial_c + (size_t)q * MH + o4);
        s.x += v.x; s.y += v.y; s.z += v.z; s.w += v.w;
    }
    s.x = fmaxf(s.x, 0.f); s.y = fmaxf(s.y, 0.f); s.z = fmaxf(s.z, 0.f); s.w = fmaxf(s.w, 0.f);
    *(float4*)(child0 + o4) = s;
}

// exists_logits[m] = child0[m,:] . W_exists + b_exists ; one wave per m
__global__ void exists_kernel(const float* __restrict__ child0, const float* __restrict__ Wex,
                              const float* __restrict__ bex, float* __restrict__ exists,
                              int* __restrict__ node_ok) {
    int wid = threadIdx.x >> 6, lane = threadIdx.x & 63;
    int m = blockIdx.x * 4 + wid;
    float s = 0.f;
    #pragma unroll
    for (int k = lane; k < HDIM; k += 64) s += child0[m * HDIM + k] * Wex[k];
    #pragma unroll
    for (int off = 32; off; off >>= 1) s += __shfl_down(s, off);
    if (lane == 0) {
        float v = s + bex[0];
        exists[m] = v;
        node_ok[m] = (v > 0.f) ? 1 : 0;
    }
}

// ---- split-K GEMM partials (dual-B generic) ----
template<int PERM>
__global__ void spk_gemm(const float* __restrict__ A, int K,
                         const float* __restrict__ B1, int N1,
                         const float* __restrict__ B2, int N2,
                         float* __restrict__ partial) {
    __shared__ float As[4][256];
    int t = threadIdx.x;
    int NT = N1 + N2;
    int m0 = blockIdx.y * 4;
    int kc = blockIdx.z * 256;
    {
        int row = t >> 6, c4 = (t & 63) * 4;
        int m = m0 + row, k = kc + c4;
        float4 a = PERM ? *(const float4*)(A + (k >> 9) * MH + m * HDIM + (k & 511))
                        : *(const float4*)(A + (size_t)m * K + k);
        *(float4*)&As[row][c4] = a;
    }
    __syncthreads();
    int col = blockIdx.x * 64 + (t & 63);
    int row = t >> 6;
    int m = m0 + row;
    if (col >= NT) return;
    bool second = col >= N1;
    const float* B = second ? B2 : B1;
    int nn = second ? col - N1 : col;
    int NN = second ? N2 : N1;
    float acc = 0.f;
    const float* bp = B + (size_t)kc * NN + nn;
    #pragma unroll 8
    for (int kk = 0; kk < 256; ++kk) acc += As[row][kk] * bp[(size_t)kk * NN];
    partial[((size_t)blockIdx.z * M_NODES + m) * NT + col] = acc;
}

__global__ void spk_reduce(const float* __restrict__ partial, int k_chunks,
                           const float* __restrict__ bias1, int relu1,
                           float* __restrict__ C1, int N1,
                           const float* __restrict__ bias2, int relu2,
                           float* __restrict__ C2, int N2) {
    int NT = N1 + N2;
    int id = blockIdx.x * 256 + threadIdx.x;
    if (id >= M_NODES * NT) return;
    int m = id / NT, col = id - m * NT;
    float s = 0.f;
    for (int kc = 0; kc < k_chunks; ++kc)
        s += partial[((size_t)kc * M_NODES + m) * NT + col];
    if (col < N1) {
        s += bias1 ? bias1[col] : 0.f;
        if (relu1) s = fmaxf(s, 0.f);
        C1[(size_t)m * N1 + col] = s;
    } else {
        int nn = col - N1;
        s += bias2 ? bias2[nn] : 0.f;
        if (relu2) s = fmaxf(s, 0.f);
        C2[(size_t)m * N2 + nn] = s;
    }
}

// ---- quad split-K GEMM: 4 B-matrices each [512,512], NT=2048 ----
__global__ void spk_gemm4(const float* __restrict__ A,
                          const float* __restrict__ B0, const float* __restrict__ B1,
                          const float* __restrict__ B2, const float* __restrict__ B3,
                          float* __restrict__ partial) {
    __shared__ float As[4][256];
    int t = threadIdx.x;
    int m0 = blockIdx.y * 4;
    int kc = blockIdx.z * 256;
    {
        int row = t >> 6, c4 = (t & 63) * 4;
        *(float4*)&As[row][c4] = *(const float4*)(A + (size_t)(m0 + row) * 512 + kc + c4);
    }
    __syncthreads();
    int col = blockIdx.x * 64 + (t & 63);      // < 2048
    int row = t >> 6;
    int m = m0 + row;
    int which = col >> 9, nn = col & 511;
    const float* B = (which == 0) ? B0 : (which == 1) ? B1 : (which == 2) ? B2 : B3;
    float acc = 0.f;
    const float* bp = B + (size_t)kc * 512 + nn;
    #pragma unroll 8
    for (int kk = 0; kk < 256; ++kk) acc += As[row][kk] * bp[(size_t)kk * 512];
    partial[((size_t)blockIdx.z * M_NODES + m) * 2048 + col] = acc;
}

__global__ void spk_reduce4(const float* __restrict__ partial,
                            const float* __restrict__ bias0, const float* __restrict__ bias2,
                            float* __restrict__ O0, float* __restrict__ O1,
                            float* __restrict__ O2, float* __restrict__ O3) {
    int id = blockIdx.x * 256 + threadIdx.x;   // grid 800 -> id < 204800
    int m = id >> 11, col = id & 2047;
    int which = col >> 9, nn = col & 511;
    float s = partial[(size_t)m * 2048 + col] + partial[(size_t)(M_NODES + m) * 2048 + col];
    if (which == 0) { O0[m * 512 + nn] = s + bias0[nn]; }
    else if (which == 1) { O1[m * 512 + nn] = s; }
    else if (which == 2) { O2[m * 512 + nn] = s + bias2[nn]; }
    else { O3[m * 512 + nn] = s; }
}

// elog[i,j,t] = relu(Xi[i]+Xj[j]) . W_ee[t] + b_ee[t] ; one wave per (i,j) pair
__global__ void elog_kernel(const float* __restrict__ Xi, const float* __restrict__ Xj,
                            const float* __restrict__ Wee, const float* __restrict__ bee,
                            const int* __restrict__ node_ok,
                            float* __restrict__ elog, int* __restrict__ any_flag) {
    int wid = threadIdx.x >> 6, lane = threadIdx.x & 63;
    int pair = blockIdx.x * 4 + wid;
    int i = pair / M_NODES, j = pair - (pair / M_NODES) * M_NODES;
    float s0 = 0.f, s1 = 0.f, s2 = 0.f, s3 = 0.f;
    #pragma unroll
    for (int k = lane; k < HDIM; k += 64) {
        float v = fmaxf(Xi[i * HDIM + k] + Xj[j * HDIM + k], 0.f);
        s0 += v * Wee[k];          s1 += v * Wee[HDIM + k];
        s2 += v * Wee[2*HDIM + k]; s3 += v * Wee[3*HDIM + k];
    }
    #pragma unroll
    for (int off = 32; off; off >>= 1) {
        s0 += __shfl_down(s0, off); s1 += __shfl_down(s1, off);
        s2 += __shfl_down(s2, off); s3 += __shfl_down(s3, off);
    }
    if (lane == 0) {
        bool ok = node_ok[i] && node_ok[j];
        float lg0 = s0 + bee[0], lg1 = s1 + bee[1], lg2 = s2 + bee[2], lg3 = s3 + bee[3];
        elog[pair * 4 + 0] = lg0; elog[pair * 4 + 1] = lg1;
        elog[pair * 4 + 2] = lg2; elog[pair * 4 + 3] = lg3;
        bool any = ok && (lg0 > 0.f || lg1 > 0.f || lg2 > 0.f || lg3 > 0.f);
        if (any && *(volatile int*)any_flag == 0) atomicOr(any_flag, 1);
    }
}

// ---- MFMA message step ----
// block (hseg, jt, i): EL[16 j][512 k] bf16 LDS tile; C = EL @ W3 via 16x16x32 MFMA;
// epilogue: partial[jt][i][h] = sum_{j in tile, t} mask*relu(A[i,h]+B[j,h]+C+lg*W4[t,h])
// grid dim3(2, 7, 100), block 256 (4 waves; wave w owns h-cols h0w..h0w+63).
__global__ void msgmfma_kernel(const float* __restrict__ Xi, const float* __restrict__ Xj,
                               const float* __restrict__ Abuf, const float* __restrict__ Bbuf,
                               const short* __restrict__ W3t, const float* __restrict__ W4,
                               const float* __restrict__ elog, const int* __restrict__ node_ok,
                               float* __restrict__ partial) {
    __shared__ short ELb[16][520];             // bf16, +8 pad -> 2-way-free b128 reads
    int i = blockIdx.z;
    int jt = blockIdx.y;
    int hseg = blockIdx.x;
    int t = threadIdx.x;
    int wave = t >> 6, lane = t & 63;
    int j0 = jt * 16;
    int h0w = hseg * 256 + wave * 64;

    // build EL tile: 2048 float4-slots / 256 threads = 8 each
    #pragma unroll
    for (int s = 0; s < 8; ++s) {
        int slot = t + s * 256;
        int row = slot >> 7;                   // 0..15
        int k0 = (slot & 127) * 4;
        int j = j0 + row;
        short4 b;
        if (j < M_NODES) {
            float4 xi = *(const float4*)(Xi + (size_t)i * HDIM + k0);
            float4 xj = *(const float4*)(Xj + (size_t)j * HDIM + k0);
            b.x = f2b(fmaxf(xi.x + xj.x, 0.f));
            b.y = f2b(fmaxf(xi.y + xj.y, 0.f));
            b.z = f2b(fmaxf(xi.z + xj.z, 0.f));
            b.w = f2b(fmaxf(xi.w + xj.w, 0.f));
        } else {
            b.x = b.y = b.z = b.w = 0;
        }
        *(short4*)&ELb[row][k0] = b;
    }
    __syncthreads();

    int n = lane & 15, quad = lane >> 4;
    float4v acc[4];
    #pragma unroll
    for (int nt = 0; nt < 4; ++nt) acc[nt] = (float4v){0.f, 0.f, 0.f, 0.f};

    // K-loop: 16 steps of k=32
    for (int kc = 0; kc < 16; ++kc) {
        int koff = kc * 32 + quad * 8;
        short8v a = *(const short8v*)&ELb[n][koff];   // A[m=n][k]
        #pragma unroll
        for (int nt = 0; nt < 4; ++nt) {
            int hcol = h0w + nt * 16 + n;
            short8v b = *(const short8v*)(W3t + (size_t)hcol * 512 + koff);  // B[k][n=hcol]
            acc[nt] = __builtin_amdgcn_mfma_f32_16x16x32_bf16(a, b, acc[nt], 0, 0, 0);
        }
    }

    // epilogue: C/D layout col=lane&15, row=quad*4+reg
    bool oki = node_ok[i] != 0;
    #pragma unroll
    for (int nt = 0; nt < 4; ++nt) {
        int hcol = h0w + nt * 16 + n;
        float aval = Abuf[(size_t)i * HDIM + hcol];
        float w40 = W4[hcol], w41 = W4[HDIM + hcol], w42 = W4[2*HDIM + hcol], w43 = W4[3*HDIM + hcol];
        float s = 0.f;
        #pragma unroll
        for (int reg = 0; reg < 4; ++reg) {
            int j = j0 + quad * 4 + reg;
            if (j < M_NODES && oki && node_ok[j]) {
                float s0 = aval + Bbuf[(size_t)j * HDIM + hcol] + acc[nt][reg];
                const float* lgp = elog + ((size_t)i * M_NODES + j) * 4;
                float lg;
                lg = lgp[0]; if (lg > 0.f) s += fmaxf(s0 + lg * w40, 0.f);
                lg = lgp[1]; if (lg > 0.f) s += fmaxf(s0 + lg * w41, 0.f);
                lg = lgp[2]; if (lg > 0.f) s += fmaxf(s0 + lg * w42, 0.f);
                lg = lgp[3]; if (lg > 0.f) s += fmaxf(s0 + lg * w43, 0.f);
            }
        }
        s += __shfl_xor(s, 16);
        s += __shfl_xor(s, 32);
        if (lane < 16) partial[(size_t)jt * MH + (size_t)i * HDIM + hcol] = s;
    }
}

// fold 7 jt-partials + any_edge select
__global__ void msgreduce_kernel(const float* __restrict__ partial,
                                 const float* __restrict__ child_prev,
                                 float* __restrict__ child_next,
                                 const int* __restrict__ any_flag) {
    int id = blockIdx.x * 256 + threadIdx.x;   // grid 200
    float s = 0.f;
    #pragma unroll
    for (int jc = 0; jc < 7; ++jc) s += partial[(size_t)jc * MH + id];
    child_next[id] = (*any_flag) ? s : child_prev[id];
}

// assemble outputs -> f32
__global__ void cast_kernel(const float* __restrict__ childout, const float* __restrict__ sem,
                            const float* __restrict__ exists, const float* __restrict__ elog,
                            float* __restrict__ out) {
    int id = blockIdx.x * 256 + threadIdx.x;
    if (id >= 97000) return;
    float v;
    if (id < 51200)       v = childout[id];
    else if (id < 56900)  v = sem[id - 51200];
    else if (id < 57000)  v = exists[id - 56900];
    else                  v = elog[id - 57000];
    out[id] = v;
}

extern "C" void kernel_launch(void* const* d_in, const int* in_sizes, int n_in,
                              void* d_out, int out_size, void* d_ws, size_t ws_size,
                              hipStream_t stream) {
    const float* parent   = (const float*)d_in[0];
    const float* W_parent = (const float*)d_in[1];
    const float* b_parent = (const float*)d_in[2];
    const float* W_exists = (const float*)d_in[3];
    const float* b_exists = (const float*)d_in[4];
    const float* W_el     = (const float*)d_in[5];
    const float* b_el     = (const float*)d_in[6];
    const float* W_ee     = (const float*)d_in[7];
    const float* b_ee     = (const float*)d_in[8];
    const float* W_ne     = (const float*)d_in[9];
    const float* b_ne     = (const float*)d_in[10];
    const float* W_child  = (const float*)d_in[11];
    const float* b_child  = (const float*)d_in[12];
    const float* W_sem    = (const float*)d_in[13];
    const float* b_sem    = (const float*)d_in[14];
    const float* W_child2 = (const float*)d_in[15];
    const float* b_child2 = (const float*)d_in[16];
    float* out = (float*)d_out;

    // workspace ~3.8 MB; scratch aliases child-partials / spk partials / msg partials
    float* ws = (float*)d_ws;
    float* child_bufs = ws;                    // 3 * 51200
    float* Xi       = ws + 3 * MH;             // 51200
    float* Xj       = Xi + MH;
    float* Abuf     = Xj + MH;
    float* Bbuf     = Abuf + MH;
    float* elog     = Bbuf + MH;               // 40000
    float* exists   = elog + 40000;            // 100
    int*   node_ok  = (int*)(exists + 100);    // 100
    int*   flag     = node_ok + M_NODES;       // 1 (+pad)
    float* scratch  = (float*)(flag + 28);     // 409600 f32 (aliased lifetimes)
    short* W3t      = (short*)(scratch + 409600);  // 2*512*512 bf16 = 512 KB
    // aliases (dead after msg iterations)
    float* hbuf     = Xi;
    float* sembuf   = Xj;
    float* childout = Abuf;

    hipMemsetAsync(flag, 0, sizeof(int), stream);

    // 0. W3 -> transposed bf16 (both iterations)
    w3prep<<<dim3(16, 16, 2), 256, 0, stream>>>(W_ne, W3t);

    // 1. child0 (split-K x8, float4)
    child_spk<<<dim3(50, 8), 256, 0, stream>>>(parent, W_parent, scratch);
    child_reduce<<<50, 256, 0, stream>>>(scratch, b_parent, child_bufs);

    // 2. exists logits + node_ok
    exists_kernel<<<25, 256, 0, stream>>>(child_bufs, W_exists, b_exists, exists, node_ok);

    // 3. Xi | Xj | A0 | B0 (quad split-K, one launch)
    spk_gemm4<<<dim3(32, 25, 2), 256, 0, stream>>>(child_bufs,
        W_el, W_el + 512 * 512, W_ne, W_ne + 512 * 512, scratch);
    spk_reduce4<<<800, 256, 0, stream>>>(scratch, b_el, b_ne, Xi, Xj, Abuf, Bbuf);

    // 4. edge_exists_logits + any_edge flag
    elog_kernel<<<2500, 256, 0, stream>>>(Xi, Xj, W_ee, b_ee, node_ok, elog, flag);

    // 5. message-passing iterations (MFMA)
    for (int it = 0; it < 2; ++it) {
        const float* cprev = child_bufs + it * MH;
        float* cnext = child_bufs + (it + 1) * MH;
        if (it == 1) {  // A1|B1 from child1
            spk_gemm<0><<<dim3(16, 25, 2), 256, 0, stream>>>(cprev, 512,
                W_ne + WNE_IT, 512, W_ne + WNE_IT + 512 * 512, 512, scratch);
            spk_reduce<<<400, 256, 0, stream>>>(scratch, 2, b_ne + 512, 0, Abuf, 512,
                                                nullptr, 0, Bbuf, 512);
        }
        msgmfma_kernel<<<dim3(2, 7, M_NODES), 256, 0, stream>>>(
            Xi, Xj, Abuf, Bbuf,
            W3t + (size_t)it * 262144,
            W_ne + (size_t)it * WNE_IT + 1536 * 512,   // W4
            elog, node_ok, scratch);
        msgreduce_kernel<<<200, 256, 0, stream>>>(scratch, cprev, cnext, flag);
    }

    // 6. heads
    spk_gemm<1><<<dim3(8, 25, 6), 256, 0, stream>>>(child_bufs, 1536,
        W_child, 512, nullptr, 0, scratch);
    spk_reduce<<<200, 256, 0, stream>>>(scratch, 6, b_child, 1, hbuf, 512,
                                        nullptr, 0, (float*)nullptr, 0);
    spk_gemm<0><<<dim3(9, 25, 2), 256, 0, stream>>>(hbuf, 512,
        W_child2, 512, W_sem, 57, scratch);
    spk_reduce<<<223, 256, 0, stream>>>(scratch, 2, b_child2, 1, childout, 512,
                                        b_sem, 0, sembuf, 57);

    // 7. assemble f32 output
    cast_kernel<<<380, 256, 0, stream>>>(childout, sembuf, exists, elog, out);
}

// Round 9
// 408.594 us; speedup vs baseline: 4.2986x; 1.0639x over previous
//
#include <hip/hip_runtime.h>

#define M_NODES 100
#define HDIM 512
#define MH (M_NODES*HDIM)       // 51200
#define MM2 (M_NODES*M_NODES)   // 10000
#define WNE_IT (1540*512)

typedef __attribute__((ext_vector_type(8))) short short8v;   // 8 bf16 (4 VGPRs)
typedef __attribute__((ext_vector_type(4))) float float4v;   // MFMA acc

static __device__ __forceinline__ short f2b(float f) {
    union { float f; unsigned u; } v; v.f = f;
    unsigned r = (v.u + 0x7FFF + ((v.u >> 16) & 1)) >> 16;   // RNE
    return (short)r;
}

// ---- W3 prep: transpose + bf16 convert, both iterations ----
__global__ void w3prep(const float* __restrict__ W_ne, short* __restrict__ W3t) {
    __shared__ float tile[32][33];
    int it = blockIdx.z, kt = blockIdx.x, ht = blockIdx.y;
    const float* W3 = W_ne + (size_t)it * WNE_IT + 1024 * 512;
    int tx = threadIdx.x & 31, ty = threadIdx.x >> 5;        // ty 0..7
    #pragma unroll
    for (int r = 0; r < 4; ++r) {
        int k = kt * 32 + ty * 4 + r;
        tile[ty * 4 + r][tx] = W3[(size_t)k * 512 + ht * 32 + tx];
    }
    __syncthreads();
    #pragma unroll
    for (int r = 0; r < 4; ++r) {
        int h = ht * 32 + ty * 4 + r;
        W3t[(size_t)it * 262144 + (size_t)h * 512 + kt * 32 + tx] = f2b(tile[tx][ty * 4 + r]);
    }
}

// ---- child = relu(parent @ W_parent + b_parent), split-K x8, float4 ----
__global__ void child_spk(const float* __restrict__ parent, const float* __restrict__ Wp,
                          float* __restrict__ partial_c) {
    __shared__ float p[64];
    int t = threadIdx.x;
    int kc = blockIdx.y * 64;
    if (t < 64) p[t] = parent[kc + t];
    __syncthreads();
    int o4 = (blockIdx.x * 256 + t) * 4;
    float4 acc = make_float4(0.f, 0.f, 0.f, 0.f);
    #pragma unroll 4
    for (int k = 0; k < 64; ++k) {
        float4 w = *(const float4*)(Wp + (size_t)(kc + k) * MH + o4);
        float pv = p[k];
        acc.x += pv * w.x; acc.y += pv * w.y; acc.z += pv * w.z; acc.w += pv * w.w;
    }
    *(float4*)(partial_c + (size_t)blockIdx.y * MH + o4) = acc;
}

// fused: fold child partials + relu + exists logits + node_ok. block = 2 rows.
__global__ void child_red_ex(const float* __restrict__ partial_c, const float* __restrict__ bp,
                             const float* __restrict__ Wex, const float* __restrict__ bex,
                             float* __restrict__ child0, float* __restrict__ exists,
                             int* __restrict__ node_ok) {
    __shared__ float red[256];
    int t = threadIdx.x;
    int o4 = (blockIdx.x * 256 + t) * 4;
    float4 s = *(const float4*)(bp + o4);
    #pragma unroll
    for (int q = 0; q < 8; ++q) {
        float4 v = *(const float4*)(partial_c + (size_t)q * MH + o4);
        s.x += v.x; s.y += v.y; s.z += v.z; s.w += v.w;
    }
    s.x = fmaxf(s.x, 0.f); s.y = fmaxf(s.y, 0.f); s.z = fmaxf(s.z, 0.f); s.w = fmaxf(s.w, 0.f);
    *(float4*)(child0 + o4) = s;
    int col = o4 & 511;
    float4 w = *(const float4*)(Wex + col);
    red[t] = s.x * w.x + s.y * w.y + s.z * w.z + s.w * w.w;
    __syncthreads();
    for (int st = 64; st; st >>= 1) {
        if ((t & 127) < st) red[t] += red[t + st];
        __syncthreads();
    }
    if ((t & 127) == 0) {
        int m = blockIdx.x * 2 + (t >> 7);
        float v = red[t] + bex[0];
        exists[m] = v;
        node_ok[m] = (v > 0.f) ? 1 : 0;
    }
}

// ---- split-K GEMM partials (dual-B generic) ----
template<int PERM>
__global__ void spk_gemm(const float* __restrict__ A, int K,
                         const float* __restrict__ B1, int N1,
                         const float* __restrict__ B2, int N2,
                         float* __restrict__ partial) {
    __shared__ float As[4][256];
    int t = threadIdx.x;
    int NT = N1 + N2;
    int m0 = blockIdx.y * 4;
    int kc = blockIdx.z * 256;
    {
        int row = t >> 6, c4 = (t & 63) * 4;
        int m = m0 + row, k = kc + c4;
        float4 a = PERM ? *(const float4*)(A + (k >> 9) * MH + m * HDIM + (k & 511))
                        : *(const float4*)(A + (size_t)m * K + k);
        *(float4*)&As[row][c4] = a;
    }
    __syncthreads();
    int col = blockIdx.x * 64 + (t & 63);
    int row = t >> 6;
    int m = m0 + row;
    if (col >= NT) return;
    bool second = col >= N1;
    const float* B = second ? B2 : B1;
    int nn = second ? col - N1 : col;
    int NN = second ? N2 : N1;
    float acc = 0.f;
    const float* bp = B + (size_t)kc * NN + nn;
    #pragma unroll 8
    for (int kk = 0; kk < 256; ++kk) acc += As[row][kk] * bp[(size_t)kk * NN];
    partial[((size_t)blockIdx.z * M_NODES + m) * NT + col] = acc;
}

__global__ void spk_reduce(const float* __restrict__ partial, int k_chunks,
                           const float* __restrict__ bias1, int relu1,
                           float* __restrict__ C1, int N1,
                           const float* __restrict__ bias2, int relu2,
                           float* __restrict__ C2, int N2) {
    int NT = N1 + N2;
    int id = blockIdx.x * 256 + threadIdx.x;
    if (id >= M_NODES * NT) return;
    int m = id / NT, col = id - m * NT;
    float s = 0.f;
    for (int kc = 0; kc < k_chunks; ++kc)
        s += partial[((size_t)kc * M_NODES + m) * NT + col];
    if (col < N1) {
        s += bias1 ? bias1[col] : 0.f;
        if (relu1) s = fmaxf(s, 0.f);
        C1[(size_t)m * N1 + col] = s;
    } else {
        int nn = col - N1;
        s += bias2 ? bias2[nn] : 0.f;
        if (relu2) s = fmaxf(s, 0.f);
        C2[(size_t)m * N2 + nn] = s;
    }
}

// ---- quad split-K GEMM: 4 B-matrices each [512,512], NT=2048 ----
__global__ void spk_gemm4(const float* __restrict__ A,
                          const float* __restrict__ B0, const float* __restrict__ B1,
                          const float* __restrict__ B2, const float* __restrict__ B3,
                          float* __restrict__ partial) {
    __shared__ float As[4][256];
    int t = threadIdx.x;
    int m0 = blockIdx.y * 4;
    int kc = blockIdx.z * 256;
    {
        int row = t >> 6, c4 = (t & 63) * 4;
        *(float4*)&As[row][c4] = *(const float4*)(A + (size_t)(m0 + row) * 512 + kc + c4);
    }
    __syncthreads();
    int col = blockIdx.x * 64 + (t & 63);
    int row = t >> 6;
    int m = m0 + row;
    int which = col >> 9, nn = col & 511;
    const float* B = (which == 0) ? B0 : (which == 1) ? B1 : (which == 2) ? B2 : B3;
    float acc = 0.f;
    const float* bp = B + (size_t)kc * 512 + nn;
    #pragma unroll 8
    for (int kk = 0; kk < 256; ++kk) acc += As[row][kk] * bp[(size_t)kk * 512];
    partial[((size_t)blockIdx.z * M_NODES + m) * 2048 + col] = acc;
}

__global__ void spk_reduce4(const float* __restrict__ partial,
                            const float* __restrict__ bias0, const float* __restrict__ bias2,
                            float* __restrict__ O0, float* __restrict__ O1,
                            float* __restrict__ O2, float* __restrict__ O3) {
    int id = blockIdx.x * 256 + threadIdx.x;
    int m = id >> 11, col = id & 2047;
    int which = col >> 9, nn = col & 511;
    float s = partial[(size_t)m * 2048 + col] + partial[(size_t)(M_NODES + m) * 2048 + col];
    if (which == 0) { O0[m * 512 + nn] = s + bias0[nn]; }
    else if (which == 1) { O1[m * 512 + nn] = s; }
    else if (which == 2) { O2[m * 512 + nn] = s + bias2[nn]; }
    else { O3[m * 512 + nn] = s; }
}

// elog + active-j compaction; one wave per (i,j) pair, float4 loads
__global__ void elog_kernel(const float* __restrict__ Xi, const float* __restrict__ Xj,
                            const float* __restrict__ Wee, const float* __restrict__ bee,
                            const int* __restrict__ node_ok,
                            float* __restrict__ elog, int* __restrict__ any_flag,
                            int* __restrict__ jcount, int* __restrict__ jlist) {
    int wid = threadIdx.x >> 6, lane = threadIdx.x & 63;
    int pair = blockIdx.x * 4 + wid;
    int i = pair / M_NODES, j = pair - (pair / M_NODES) * M_NODES;
    int k0 = lane * 8;
    float4 xa = *(const float4*)(Xi + (size_t)i * HDIM + k0);
    float4 xb = *(const float4*)(Xi + (size_t)i * HDIM + k0 + 4);
    float4 ya = *(const float4*)(Xj + (size_t)j * HDIM + k0);
    float4 yb = *(const float4*)(Xj + (size_t)j * HDIM + k0 + 4);
    float e0 = fmaxf(xa.x + ya.x, 0.f), e1 = fmaxf(xa.y + ya.y, 0.f);
    float e2 = fmaxf(xa.z + ya.z, 0.f), e3 = fmaxf(xa.w + ya.w, 0.f);
    float e4 = fmaxf(xb.x + yb.x, 0.f), e5 = fmaxf(xb.y + yb.y, 0.f);
    float e6 = fmaxf(xb.z + yb.z, 0.f), e7 = fmaxf(xb.w + yb.w, 0.f);
    float s[4];
    #pragma unroll
    for (int t = 0; t < 4; ++t) {
        float4 wa = *(const float4*)(Wee + t * HDIM + k0);
        float4 wb = *(const float4*)(Wee + t * HDIM + k0 + 4);
        s[t] = e0*wa.x + e1*wa.y + e2*wa.z + e3*wa.w + e4*wb.x + e5*wb.y + e6*wb.z + e7*wb.w;
    }
    #pragma unroll
    for (int off = 32; off; off >>= 1) {
        s[0] += __shfl_down(s[0], off); s[1] += __shfl_down(s[1], off);
        s[2] += __shfl_down(s[2], off); s[3] += __shfl_down(s[3], off);
    }
    if (lane == 0) {
        bool ok = node_ok[i] && node_ok[j];
        float lg0 = s[0] + bee[0], lg1 = s[1] + bee[1], lg2 = s[2] + bee[2], lg3 = s[3] + bee[3];
        elog[pair * 4 + 0] = lg0; elog[pair * 4 + 1] = lg1;
        elog[pair * 4 + 2] = lg2; elog[pair * 4 + 3] = lg3;
        bool any = ok && (lg0 > 0.f || lg1 > 0.f || lg2 > 0.f || lg3 > 0.f);
        if (any) {
            int slot = atomicAdd(&jcount[i], 1);
            jlist[i * 112 + slot] = j;
            if (*(volatile int*)any_flag == 0) atomicOr(any_flag, 1);
        }
    }
}

// ---- MFMA message step, compacted j, merged hseg ----
// block (jt, i), 512 threads (8 waves; wave w owns h-cols w*64..w*64+63).
__global__ __launch_bounds__(512) void
msgmfma_kernel(const float* __restrict__ Xi, const float* __restrict__ Xj,
               const float* __restrict__ Abuf, const float* __restrict__ Bbuf,
               const short* __restrict__ W3t, const float* __restrict__ W4,
               const float* __restrict__ elog, const int* __restrict__ jcount,
               const int* __restrict__ jlist, float* __restrict__ partial) {
    __shared__ short ELb[16][520];             // bf16, +8 pad
    __shared__ int jrow[16];
    int i = blockIdx.y;
    int jt = blockIdx.x;
    int jcnt = jcount[i];
    int j0 = jt * 16;
    if (j0 >= jcnt) return;                    // sparse early-exit
    int t = threadIdx.x;
    int wave = t >> 6, lane = t & 63;

    if (t < 16) jrow[t] = (j0 + t < jcnt) ? jlist[i * 112 + j0 + t] : -1;
    __syncthreads();
    // build EL tile: 2048 float4-slots / 512 threads = 4 each
    #pragma unroll
    for (int s = 0; s < 4; ++s) {
        int slot = t + s * 512;
        int row = slot >> 7;
        int k0 = (slot & 127) * 4;
        int j = jrow[row];
        short4 b;
        if (j >= 0) {
            float4 xi = *(const float4*)(Xi + (size_t)i * HDIM + k0);
            float4 xj = *(const float4*)(Xj + (size_t)j * HDIM + k0);
            b.x = f2b(fmaxf(xi.x + xj.x, 0.f));
            b.y = f2b(fmaxf(xi.y + xj.y, 0.f));
            b.z = f2b(fmaxf(xi.z + xj.z, 0.f));
            b.w = f2b(fmaxf(xi.w + xj.w, 0.f));
        } else {
            b.x = b.y = b.z = b.w = 0;
        }
        *(short4*)&ELb[row][k0] = b;
    }
    __syncthreads();

    int n = lane & 15, quad = lane >> 4;
    int h0w = wave * 64;
    float4v acc[4];
    #pragma unroll
    for (int nt = 0; nt < 4; ++nt) acc[nt] = (float4v){0.f, 0.f, 0.f, 0.f};

    for (int kc = 0; kc < 16; ++kc) {
        int koff = kc * 32 + quad * 8;
        short8v a = *(const short8v*)&ELb[n][koff];
        #pragma unroll
        for (int nt = 0; nt < 4; ++nt) {
            int hcol = h0w + nt * 16 + n;
            short8v b = *(const short8v*)(W3t + (size_t)hcol * 512 + koff);
            acc[nt] = __builtin_amdgcn_mfma_f32_16x16x32_bf16(a, b, acc[nt], 0, 0, 0);
        }
    }

    // epilogue: C/D col=lane&15 -> hcol, row=quad*4+reg -> tile j-row
    #pragma unroll
    for (int nt = 0; nt < 4; ++nt) {
        int hcol = h0w + nt * 16 + n;
        float aval = Abuf[(size_t)i * HDIM + hcol];
        float w40 = W4[hcol], w41 = W4[HDIM + hcol], w42 = W4[2*HDIM + hcol], w43 = W4[3*HDIM + hcol];
        float s = 0.f;
        #pragma unroll
        for (int reg = 0; reg < 4; ++reg) {
            int jj = jrow[quad * 4 + reg];
            if (jj >= 0) {
                float s0 = aval + Bbuf[(size_t)jj * HDIM + hcol] + acc[nt][reg];
                const float* lgp = elog + ((size_t)i * M_NODES + jj) * 4;
                float lg;
                lg = lgp[0]; if (lg > 0.f) s += fmaxf(s0 + lg * w40, 0.f);
                lg = lgp[1]; if (lg > 0.f) s += fmaxf(s0 + lg * w41, 0.f);
                lg = lgp[2]; if (lg > 0.f) s += fmaxf(s0 + lg * w42, 0.f);
                lg = lgp[3]; if (lg > 0.f) s += fmaxf(s0 + lg * w43, 0.f);
            }
        }
        s += __shfl_xor(s, 16);
        s += __shfl_xor(s, 32);
        if (lane < 16) partial[(size_t)jt * MH + (size_t)i * HDIM + hcol] = s;
    }
}

// fold live jt-partials + any_edge select
__global__ void msgreduce_kernel(const float* __restrict__ partial,
                                 const float* __restrict__ child_prev,
                                 float* __restrict__ child_next,
                                 const int* __restrict__ any_flag,
                                 const int* __restrict__ jcount) {
    int id = blockIdx.x * 256 + threadIdx.x;   // grid 200
    int i = id >> 9;
    int ntiles = (jcount[i] + 15) >> 4;
    float s = 0.f;
    for (int jc = 0; jc < ntiles; ++jc) s += partial[(size_t)jc * MH + id];
    child_next[id] = (*any_flag) ? s : child_prev[id];
}

// assemble outputs -> f32
__global__ void cast_kernel(const float* __restrict__ childout, const float* __restrict__ sem,
                            const float* __restrict__ exists, const float* __restrict__ elog,
                            float* __restrict__ out) {
    int id = blockIdx.x * 256 + threadIdx.x;
    if (id >= 97000) return;
    float v;
    if (id < 51200)       v = childout[id];
    else if (id < 56900)  v = sem[id - 51200];
    else if (id < 57000)  v = exists[id - 56900];
    else                  v = elog[id - 57000];
    out[id] = v;
}

extern "C" void kernel_launch(void* const* d_in, const int* in_sizes, int n_in,
                              void* d_out, int out_size, void* d_ws, size_t ws_size,
                              hipStream_t stream) {
    const float* parent   = (const float*)d_in[0];
    const float* W_parent = (const float*)d_in[1];
    const float* b_parent = (const float*)d_in[2];
    const float* W_exists = (const float*)d_in[3];
    const float* b_exists = (const float*)d_in[4];
    const float* W_el     = (const float*)d_in[5];
    const float* b_el     = (const float*)d_in[6];
    const float* W_ee     = (const float*)d_in[7];
    const float* b_ee     = (const float*)d_in[8];
    const float* W_ne     = (const float*)d_in[9];
    const float* b_ne     = (const float*)d_in[10];
    const float* W_child  = (const float*)d_in[11];
    const float* b_child  = (const float*)d_in[12];
    const float* W_sem    = (const float*)d_in[13];
    const float* b_sem    = (const float*)d_in[14];
    const float* W_child2 = (const float*)d_in[15];
    const float* b_child2 = (const float*)d_in[16];
    float* out = (float*)d_out;

    float* ws = (float*)d_ws;
    float* child_bufs = ws;                    // 3 * 51200
    float* Xi       = ws + 3 * MH;             // 51200
    float* Xj       = Xi + MH;
    float* Abuf     = Xj + MH;
    float* Bbuf     = Abuf + MH;
    float* elog     = Bbuf + MH;               // 40000
    float* exists   = elog + 40000;            // 100
    int*   node_ok  = (int*)(exists + 100);    // 100
    int*   flag     = node_ok + M_NODES;       // 1
    int*   jcount   = flag + 1;                // 100 (contiguous with flag for memset)
    int*   jlist    = jcount + 100;            // 100*112 = 11200
    float* scratch  = (float*)(jlist + 11200 + 7);   // 409600 f32, 16B-aligned
    short* W3t      = (short*)(scratch + 409600);    // 2*512*512 bf16 = 1 MB
    float* hbuf     = Xi;                      // aliases (dead after msg)
    float* sembuf   = Xj;
    float* childout = Abuf;

    hipMemsetAsync(flag, 0, sizeof(int) * 101, stream);   // flag + jcount

    w3prep<<<dim3(16, 16, 2), 256, 0, stream>>>(W_ne, W3t);

    child_spk<<<dim3(50, 8), 256, 0, stream>>>(parent, W_parent, scratch);
    child_red_ex<<<50, 256, 0, stream>>>(scratch, b_parent, W_exists, b_exists,
                                         child_bufs, exists, node_ok);

    spk_gemm4<<<dim3(32, 25, 2), 256, 0, stream>>>(child_bufs,
        W_el, W_el + 512 * 512, W_ne, W_ne + 512 * 512, scratch);
    spk_reduce4<<<800, 256, 0, stream>>>(scratch, b_el, b_ne, Xi, Xj, Abuf, Bbuf);

    elog_kernel<<<2500, 256, 0, stream>>>(Xi, Xj, W_ee, b_ee, node_ok, elog, flag,
                                          jcount, jlist);

    for (int it = 0; it < 2; ++it) {
        const float* cprev = child_bufs + it * MH;
        float* cnext = child_bufs + (it + 1) * MH;
        if (it == 1) {
            spk_gemm<0><<<dim3(16, 25, 2), 256, 0, stream>>>(cprev, 512,
                W_ne + WNE_IT, 512, W_ne + WNE_IT + 512 * 512, 512, scratch);
            spk_reduce<<<400, 256, 0, stream>>>(scratch, 2, b_ne + 512, 0, Abuf, 512,
                                                nullptr, 0, Bbuf, 512);
        }
        msgmfma_kernel<<<dim3(7, M_NODES), 512, 0, stream>>>(
            Xi, Xj, Abuf, Bbuf,
            W3t + (size_t)it * 262144,
            W_ne + (size_t)it * WNE_IT + 1536 * 512,
            elog, jcount, jlist, scratch);
        msgreduce_kernel<<<200, 256, 0, stream>>>(scratch, cprev, cnext, flag, jcount);
    }

    spk_gemm<1><<<dim3(8, 25, 6), 256, 0, stream>>>(child_bufs, 1536,
        W_child, 512, nullptr, 0, scratch);
    spk_reduce<<<200, 256, 0, stream>>>(scratch, 6, b_child, 1, hbuf, 512,
                                        nullptr, 0, (float*)nullptr, 0);
    spk_gemm<0><<<dim3(9, 25, 2), 256, 0, stream>>>(hbuf, 512,
        W_child2, 512, W_sem, 57, scratch);
    spk_reduce<<<223, 256, 0, stream>>>(scratch, 2, b_child2, 1, childout, 512,
                                        b_sem, 0, sembuf, 57);

    cast_kernel<<<380, 256, 0, stream>>>(childout, sembuf, exists, elog, out);
}